// Round 1
// baseline (274.078 us; speedup 1.0000x reference)
//
#include <hip/hip_runtime.h>
#include <math.h>

// UpsampleFlow3: for each query point, K=5 nearest sparse points (Euclidean),
// softmax(-dist) weights, weighted sum of sparse flows.
// B=4, N=16384, M=4096, K=5, fp32. Fused KNN+softmax+gather, no [N,M] matrix.

#define KNN 5
#define BLOCK 256
#define WAVES_PER_BLOCK 4
#define QPB 64              // queries per block (= lanes per wave)
#define MMAX 4096

// Branchless insert of (d, j) into ascending sorted top-5 (e[0] smallest).
// Outer branch is a cheap skip when no lane in the wave improves.
__device__ __forceinline__ void insert5(float d, int j, float e[KNN], int idx[KNN]) {
    if (d < e[4]) {
        const bool c3 = d < e[3], c2 = d < e[2], c1 = d < e[1], c0 = d < e[0];
        e[4]   = c3 ? e[3]   : d;                 idx[4] = c3 ? idx[3] : j;
        e[3]   = c2 ? e[2]   : (c3 ? d : e[3]);   idx[3] = c2 ? idx[2] : (c3 ? j : idx[3]);
        e[2]   = c1 ? e[1]   : (c2 ? d : e[2]);   idx[2] = c1 ? idx[1] : (c2 ? j : idx[2]);
        e[1]   = c0 ? e[0]   : (c1 ? d : e[1]);   idx[1] = c0 ? idx[0] : (c1 ? j : idx[1]);
        e[0]   = c0 ? d      : e[0];              idx[0] = c0 ? j      : idx[0];
    }
}

__global__ __launch_bounds__(BLOCK)
void upsample_flow_knn_kernel(const float* __restrict__ xyz,
                              const float* __restrict__ sxyz,
                              const float* __restrict__ sflow,
                              const int* __restrict__ rf,
                              float* __restrict__ out,
                              int N, int M, int blocksPerBatch) {
    __shared__ float4 lds_p[MMAX];                       // (x,y,z,|p|^2) scaled, 64 KB
    __shared__ float  md[QPB * WAVES_PER_BLOCK * KNN];   // merge buf: d2
    __shared__ int    mi[QPB * WAVES_PER_BLOCK * KNN];   // merge buf: idx

    const int tid  = threadIdx.x;
    const int lane = tid & 63;
    const int wid  = tid >> 6;
    const int b    = blockIdx.x / blocksPerBatch;
    const int n0   = (blockIdx.x % blocksPerBatch) * QPB;

    // resol_factor: Python int -> int32 array; defensively accept fp32 too.
    const int ri = rf[0];
    const float sigma = (ri >= 1 && ri <= 1000000) ? (float)ri : __int_as_float(ri);
    const float inv_sigma = 1.0f / sigma;   // INITIAL_RADIUS = 1.0

    // ---- stage sparse points (scaled) + their squared norms into LDS ----
    const float* sb = sxyz + (size_t)b * 3 * M;
    for (int t = tid; t < M; t += BLOCK) {
        const float px = sb[t]         * inv_sigma;
        const float py = sb[M + t]     * inv_sigma;
        const float pz = sb[2 * M + t] * inv_sigma;
        lds_p[t] = make_float4(px, py, pz, px * px + py * py + pz * pz);
    }

    // ---- per-lane query coords (coalesced) ----
    const int n  = n0 + lane;
    const int nc = (n < N) ? n : (N - 1);
    const float* qb = xyz + (size_t)b * 3 * N;
    const float qx = qb[nc]         * inv_sigma;
    const float qy = qb[N + nc]     * inv_sigma;
    const float qz = qb[2 * N + nc] * inv_sigma;
    const float qq = qx * qx + qy * qy + qz * qz;

    __syncthreads();

    // ---- scan this wave's chunk of M; all 64 lanes read the same LDS addr
    //      (pure broadcast, conflict-free) ----
    const int chunk = (M + WAVES_PER_BLOCK - 1) / WAVES_PER_BLOCK;
    const int j0 = wid * chunk;
    const int j1 = (j0 + chunk < M) ? (j0 + chunk) : M;

    float e[KNN];
    int   idx[KNN];
#pragma unroll
    for (int k = 0; k < KNN; ++k) { e[k] = 1e30f; idx[k] = 0; }

#pragma unroll 4
    for (int j = j0; j < j1; ++j) {
        const float4 p = lds_p[j];
        float t = qx * p.x;
        t = fmaf(qy, p.y, t);
        t = fmaf(qz, p.z, t);
        // reference formulation: sq = |q|^2 + |p|^2 - 2 q.p (scaled coords)
        const float d2 = fmaf(-2.0f, t, qq + p.w);
        insert5(d2, j, e, idx);
    }

    // ---- write per-wave top-5 to LDS merge buffer ----
#pragma unroll
    for (int k = 0; k < KNN; ++k) {
        md[lane * (WAVES_PER_BLOCK * KNN) + wid * KNN + k] = e[k];
        mi[lane * (WAVES_PER_BLOCK * KNN) + wid * KNN + k] = idx[k];
    }
    __syncthreads();

    // ---- wave 0: merge 4x5 -> top-5, softmax, gather flow, store ----
    if (wid == 0 && n < N) {
        float fe[KNN];
        int   fi[KNN];
#pragma unroll
        for (int k = 0; k < KNN; ++k) { fe[k] = 1e30f; fi[k] = 0; }
#pragma unroll
        for (int t = 0; t < WAVES_PER_BLOCK * KNN; ++t) {
            insert5(md[lane * (WAVES_PER_BLOCK * KNN) + t],
                    mi[lane * (WAVES_PER_BLOCK * KNN) + t], fe, fi);
        }

        // distances (match ref: sqrt(max(sq, 1e-12))), softmax over -dist
        float dist[KNN];
#pragma unroll
        for (int k = 0; k < KNN; ++k) dist[k] = sqrtf(fmaxf(fe[k], 1e-12f));
        const float dmin = dist[0];   // fe sorted ascending
        float w[KNN];
        float wsum = 0.0f;
#pragma unroll
        for (int k = 0; k < KNN; ++k) { w[k] = expf(dmin - dist[k]); wsum += w[k]; }
        const float inv_wsum = 1.0f / wsum;

        const float* fb = sflow + (size_t)b * 3 * M;
        float ax = 0.0f, ay = 0.0f, az = 0.0f;
#pragma unroll
        for (int k = 0; k < KNN; ++k) {
            const int m = fi[k];
            const float wk = w[k];
            ax = fmaf(wk, fb[m],         ax);
            ay = fmaf(wk, fb[M + m],     ay);
            az = fmaf(wk, fb[2 * M + m], az);
        }

        float* ob = out + (size_t)b * 3 * N;
        ob[n]         = ax * inv_wsum;
        ob[N + n]     = ay * inv_wsum;
        ob[2 * N + n] = az * inv_wsum;
    }
}

extern "C" void kernel_launch(void* const* d_in, const int* in_sizes, int n_in,
                              void* d_out, int out_size, void* d_ws, size_t ws_size,
                              hipStream_t stream) {
    const float* xyz   = (const float*)d_in[0];
    const float* sxyz  = (const float*)d_in[1];
    const float* sflow = (const float*)d_in[2];
    const int*   rf    = (const int*)d_in[3];
    // d_in[4] = K; fixed at 5 for this problem (hard-coded as KNN).

    const int B = 4;                        // fixed problem shape
    const int N = in_sizes[0] / (3 * B);    // 16384
    const int M = in_sizes[1] / (3 * B);    // 4096

    float* out = (float*)d_out;

    const int blocksPerBatch = (N + QPB - 1) / QPB;
    const dim3 grid(B * blocksPerBatch);
    const dim3 block(BLOCK);
    upsample_flow_knn_kernel<<<grid, block, 0, stream>>>(xyz, sxyz, sflow, rf, out,
                                                         N, M, blocksPerBatch);
}